// Round 6
// baseline (309.992 us; speedup 1.0000x reference)
//
#include <hip/hip_runtime.h>

#define NT 4096          // time samples per column
#define NCOL 4096        // 512 traces * 8 channels
#define EPT 16           // elements per thread (one chunk)
#define SORT_T 256       // threads (chunks) per array
#define BLOCK 512

__device__ __forceinline__ float b2f(int i) { return __builtin_bit_cast(float, i); }
__device__ __forceinline__ int   f2b(float f) { return __builtin_bit_cast(int, f); }

// Bank-conflict-free float4 slot for (chunk c, quarter q): rotate q by c>>1 so a
// wave's b128 ops cover all 8 bank-groups (2-way aliasing = free, m136).
__device__ __forceinline__ int slot(int c, int q) { return c * 4 + ((q + (c >> 1)) & 3); }

// Cross-lane fetch of partner lane^XM's value.
// XM 1,2,3: DPP quad_perm; XM 7: row_half_mirror; XM 8: row_ror:8;
// XM 15: row_mirror (all VALU pipe, zero DS traffic).
// XM 4,16,31: ds_swizzle BitMode xor. XM 32,63: ds_bpermute.
template <int XM>
__device__ __forceinline__ float lx(float v) {
    const int i = f2b(v);
    int r;
    if constexpr (XM == 1)       r = __builtin_amdgcn_update_dpp(0, i, 0xB1,  0xF, 0xF, true); // quad_perm [1,0,3,2]
    else if constexpr (XM == 2)  r = __builtin_amdgcn_update_dpp(0, i, 0x4E,  0xF, 0xF, true); // quad_perm [2,3,0,1]
    else if constexpr (XM == 3)  r = __builtin_amdgcn_update_dpp(0, i, 0x1B,  0xF, 0xF, true); // quad_perm [3,2,1,0]
    else if constexpr (XM == 7)  r = __builtin_amdgcn_update_dpp(0, i, 0x141, 0xF, 0xF, true); // row_half_mirror = ^7
    else if constexpr (XM == 8)  r = __builtin_amdgcn_update_dpp(0, i, 0x128, 0xF, 0xF, true); // row_ror:8 = ^8
    else if constexpr (XM == 15) r = __builtin_amdgcn_update_dpp(0, i, 0x140, 0xF, 0xF, true); // row_mirror = ^15
    else if constexpr (XM == 4)  r = __builtin_amdgcn_ds_swizzle(i, 0x101F);
    else if constexpr (XM == 16) r = __builtin_amdgcn_ds_swizzle(i, 0x401F);
    else if constexpr (XM == 31) r = __builtin_amdgcn_ds_swizzle(i, 0x7C1F);
    else {
        const int lane = (int)(threadIdx.x & 63);
        r = __builtin_amdgcn_ds_bpermute((lane ^ XM) << 2, i);
    }
    return b2f(r);
}

// compile-time ascending compare-exchange (min+max, 2 VALU)
__device__ __forceinline__ void cemin(float& a, float& b) {
    const float lo = fminf(a, b);
    const float hi = fmaxf(a, b);
    a = lo; b = hi;
}

// cross-chunk keep: 1 v_cmp + SALU mask combine + 1 v_cndmask (2 VALU)
__device__ __forceinline__ float csel(float x, float y, bool keep_min) {
    return ((x < y) == keep_min) ? x : y;
}

// intra-thread plain stages j = 8..1 (ascending)
__device__ __forceinline__ void tail8(float (&x)[EPT]) {
    #pragma unroll
    for (int j = 8; j >= 1; j >>= 1) {
        #pragma unroll
        for (int e = 0; e < EPT; ++e)
            if ((e & j) == 0) cemin(x[e], x[e | j]);
    }
}

// normalized-bitonic reversal stage over C chunks (C<=64, in-wave):
// partner chunk = c ^ (C-1), element pairing e <-> 15-e.
template <int C>
__device__ __forceinline__ void rev_wave(float (&x)[EPT], int c) {
    const bool keep_min = (c & (C >> 1)) == 0;
    float y[EPT];
    #pragma unroll
    for (int e = 0; e < EPT; ++e) y[e] = lx<C - 1>(x[EPT - 1 - e]);
    #pragma unroll
    for (int e = 0; e < EPT; ++e) x[e] = csel(x[e], y[e], keep_min);
}

// plain cross-lane stage, chunk-xor distance M (in-wave, M<=32)
template <int M>
__device__ __forceinline__ void plain_wave(float (&x)[EPT], int c) {
    const bool keep_min = (c & M) == 0;
    #pragma unroll
    for (int e = 0; e < EPT; ++e) {
        const float y = lx<M>(x[e]);
        x[e] = csel(x[e], y, keep_min);
    }
}

// cross-wave stage via LDS (b128, swizzled slots): REV -> reversal over C chunks,
// else plain xor C
template <int C, bool REV>
__device__ __forceinline__ void lds_stage(float (&x)[EPT], int c, float4* ls4) {
    #pragma unroll
    for (int q = 0; q < 4; ++q)
        ls4[slot(c, q)] = make_float4(x[4 * q], x[4 * q + 1], x[4 * q + 2], x[4 * q + 3]);
    __syncthreads();
    const int  pc       = REV ? (c ^ (C - 1)) : (c ^ C);
    const bool keep_min = REV ? ((c & (C >> 1)) == 0) : ((c & C) == 0);
    float4 p[4];
    #pragma unroll
    for (int q = 0; q < 4; ++q) p[q] = ls4[slot(pc, q)];
    const float* pw = (const float*)p;   // registers; constant indices below
    #pragma unroll
    for (int e = 0; e < EPT; ++e) {
        const float y = REV ? pw[EPT - 1 - e] : pw[e];
        x[e] = csel(x[e], y, keep_min);
    }
    __syncthreads();
}

__global__ __launch_bounds__(512) void wass_kernel(const float* __restrict__ pred,
                                                   const float* __restrict__ obs,
                                                   float* __restrict__ out) {
    __shared__ float4 lsA4[SORT_T * 4];   // 16 KB
    __shared__ float4 lsB4[SORT_T * 4];   // 16 KB
    __shared__ float  red[BLOCK / 64];

    const int bid = blockIdx.x;
    const int col = (bid & 7) * 512 + (bid >> 3);  // XCD-band swizzle

    const int t   = threadIdx.x;
    const int arr = t >> 8;          // 0 = pred, 1 = obs (wave-uniform)
    const int c   = t & 255;         // chunk index within the array
    const float* __restrict__ src = arr ? obs : pred;
    float4* ls4 = arr ? lsB4 : lsA4; // wave-uniform

    const int gbase = c * EPT;

    // ---- load 16 elements of my column chunk ----
    float x[EPT];
    #pragma unroll
    for (int e = 0; e < EPT; ++e)
        x[e] = src[(size_t)(gbase + e) * NCOL + col];

    // ---- phase 1: normalized bitonic 16-sort, fully in registers ----
    #pragma unroll
    for (int kk = 2; kk <= 16; kk <<= 1) {
        #pragma unroll
        for (int b = 0; b < EPT; b += kk) {
            #pragma unroll
            for (int e = 0; e < kk / 2; ++e)
                cemin(x[b + e], x[b + kk - 1 - e]);
        }
        #pragma unroll
        for (int j = kk / 4; j >= 1; j >>= 1) {
            #pragma unroll
            for (int e = 0; e < EPT; ++e)
                if ((e & j) == 0) cemin(x[e], x[e | j]);
        }
    }

    // ---- phase 2: normalized bitonic merges k = 32 .. 4096 ----
    // k=32
    rev_wave<2>(x, c);  tail8(x);
    // k=64
    rev_wave<4>(x, c);  plain_wave<1>(x, c); tail8(x);
    // k=128
    rev_wave<8>(x, c);  plain_wave<2>(x, c); plain_wave<1>(x, c); tail8(x);
    // k=256
    rev_wave<16>(x, c); plain_wave<4>(x, c); plain_wave<2>(x, c); plain_wave<1>(x, c); tail8(x);
    // k=512
    rev_wave<32>(x, c); plain_wave<8>(x, c); plain_wave<4>(x, c); plain_wave<2>(x, c);
    plain_wave<1>(x, c); tail8(x);
    // k=1024
    rev_wave<64>(x, c); plain_wave<16>(x, c); plain_wave<8>(x, c); plain_wave<4>(x, c);
    plain_wave<2>(x, c); plain_wave<1>(x, c); tail8(x);
    // k=2048
    lds_stage<128, true>(x, c, ls4);
    plain_wave<32>(x, c); plain_wave<16>(x, c); plain_wave<8>(x, c); plain_wave<4>(x, c);
    plain_wave<2>(x, c); plain_wave<1>(x, c); tail8(x);
    // k=4096
    lds_stage<256, true>(x, c, ls4);
    lds_stage<64, false>(x, c, ls4);
    plain_wave<32>(x, c); plain_wave<16>(x, c); plain_wave<8>(x, c); plain_wave<4>(x, c);
    plain_wave<2>(x, c); plain_wave<1>(x, c); tail8(x);

    // ---- epilogue: sorted arrays -> LDS (swizzled b128), abs-diff, reduce ----
    #pragma unroll
    for (int q = 0; q < 4; ++q)
        ls4[slot(c, q)] = make_float4(x[4 * q], x[4 * q + 1], x[4 * q + 2], x[4 * q + 3]);
    __syncthreads();

    // thread t handles half of chunk (t>>1): quarters 2*(t&1), 2*(t&1)+1
    float s = 0.0f;
    {
        const int ec = t >> 1;
        const int q0 = (t & 1) * 2;
        #pragma unroll
        for (int q = 0; q < 2; ++q) {
            const float4 a = lsA4[slot(ec, q0 + q)];
            const float4 b = lsB4[slot(ec, q0 + q)];
            s += fabsf(a.x - b.x) + fabsf(a.y - b.y) + fabsf(a.z - b.z) + fabsf(a.w - b.w);
        }
    }
    #pragma unroll
    for (int off = 32; off > 0; off >>= 1)
        s += __shfl_down(s, off, 64);
    if ((t & 63) == 0) red[t >> 6] = s;
    __syncthreads();
    if (t == 0) {
        float tot = 0.0f;
        #pragma unroll
        for (int w = 0; w < BLOCK / 64; ++w) tot += red[w];
        atomicAdd(out, tot * (1.0f / ((float)NT * (float)NCOL)));
    }
}

extern "C" void kernel_launch(void* const* d_in, const int* in_sizes, int n_in,
                              void* d_out, int out_size, void* d_ws, size_t ws_size,
                              hipStream_t stream) {
    const float* pred = (const float*)d_in[0];
    const float* obs  = (const float*)d_in[1];
    float* out = (float*)d_out;
    hipMemsetAsync(out, 0, sizeof(float), stream);
    wass_kernel<<<NCOL, BLOCK, 0, stream>>>(pred, obs, out);
}

// Round 7
// 279.353 us; speedup vs baseline: 1.1097x; 1.1097x over previous
//
#include <hip/hip_runtime.h>

#define NT 4096          // time samples per column
#define NCOL 4096        // 512 traces * 8 channels
#define EPT 64           // elements per lane: one wave sorts one whole column
#define BLOCK 512        // 8 waves: waves 0-3 pred cols w, waves 4-7 obs cols w
#define NBLOCKS 1024     // 4096 cols / 4 cols per block

__device__ __forceinline__ float b2f(int i) { return __builtin_bit_cast(float, i); }
__device__ __forceinline__ int   f2b(float f) { return __builtin_bit_cast(int, f); }

// Cross-lane fetch of partner lane^XM's value.
// XM 1,2,3 (quad_perm), 7 (row_half_mirror), 8 (row_ror:8), 15 (row_mirror): DPP,
// VALU pipe, zero DS traffic. XM 4,16,31: ds_swizzle. XM 63: ds_bpermute.
template <int XM>
__device__ __forceinline__ float lx(float v) {
    const int i = f2b(v);
    int r;
    if constexpr (XM == 1)       r = __builtin_amdgcn_update_dpp(0, i, 0xB1,  0xF, 0xF, true);
    else if constexpr (XM == 2)  r = __builtin_amdgcn_update_dpp(0, i, 0x4E,  0xF, 0xF, true);
    else if constexpr (XM == 3)  r = __builtin_amdgcn_update_dpp(0, i, 0x1B,  0xF, 0xF, true);
    else if constexpr (XM == 7)  r = __builtin_amdgcn_update_dpp(0, i, 0x141, 0xF, 0xF, true);
    else if constexpr (XM == 8)  r = __builtin_amdgcn_update_dpp(0, i, 0x128, 0xF, 0xF, true);
    else if constexpr (XM == 15) r = __builtin_amdgcn_update_dpp(0, i, 0x140, 0xF, 0xF, true);
    else if constexpr (XM == 4)  r = __builtin_amdgcn_ds_swizzle(i, 0x101F);
    else if constexpr (XM == 16) r = __builtin_amdgcn_ds_swizzle(i, 0x401F);
    else if constexpr (XM == 31) r = __builtin_amdgcn_ds_swizzle(i, 0x7C1F);
    else {
        const int lane = (int)(threadIdx.x & 63);
        r = __builtin_amdgcn_ds_bpermute((lane ^ XM) << 2, i);
    }
    return b2f(r);
}

__device__ __forceinline__ void cemin(float& a, float& b) {
    const float lo = fminf(a, b);
    const float hi = fmaxf(a, b);
    a = lo; b = hi;
}
__device__ __forceinline__ float csel(float x, float y, bool keep_min) {
    return ((x < y) == keep_min) ? x : y;
}

// plain cross-lane stage, lane-xor M, same element index
template <int M>
__device__ __forceinline__ void plain_stage(float (&x)[EPT], int L) {
    const bool km = (L & M) == 0;
    #pragma unroll
    for (int e = 0; e < EPT; ++e) {
        const float y = lx<M>(x[e]);
        x[e] = csel(x[e], y, km);
    }
}

template <int M>
__device__ __forceinline__ void plains_down(float (&x)[EPT], int L) {
    plain_stage<M>(x, L);
    if constexpr (M > 1) plains_down<M / 2>(x, L);
}

// intra-thread plain stages j = 32..1, all ascending (normalized network)
__device__ __forceinline__ void tail32(float (&x)[EPT]) {
    #pragma unroll
    for (int j = 32; j >= 1; j >>= 1) {
        #pragma unroll
        for (int e = 0; e < EPT; ++e)
            if ((e & j) == 0) cemin(x[e], x[e | j]);
    }
}

// Normalized bitonic merge of size k = 64*K (K = 2..64), fully in-wave:
// reversal: partner lane L^(K-1), element mirror e<->63-e, keep-min if (L&K/2)==0;
// then plain lane-xor stages m=K/4..1; then intra-thread tail j=32..1.
template <int K>
__device__ __forceinline__ void cross_merge(float (&x)[EPT], int L) {
    const bool km = (L & (K >> 1)) == 0;
    #pragma unroll
    for (int e = 0; e < EPT / 2; ++e) {
        const float ylo = lx<K - 1>(x[EPT - 1 - e]);   // partner's mirrored element
        const float yhi = lx<K - 1>(x[e]);
        x[e]           = csel(x[e], ylo, km);
        x[EPT - 1 - e] = csel(x[EPT - 1 - e], yhi, km);
    }
    if constexpr (K >= 4) plains_down<K / 4>(x, L);
    tail32(x);
}

// LDS: staging transpose (2 halves x 4096 words = 32 KB) unioned with
// epilogue strips (4 cols x 64 lanes x 66 words = 67.6 KB)
#define LS_WORDS 16896

__global__ __launch_bounds__(512, 4) void wass_kernel(const float* __restrict__ pred,
                                                      const float* __restrict__ obs,
                                                      float* __restrict__ out) {
    __shared__ __align__(16) float ls[LS_WORDS];

    const int bid  = blockIdx.x;
    const int cb   = (bid & 7) * 128 + (bid >> 3);   // XCD-band col-block swizzle
    const int col0 = cb * 4;

    const int t    = threadIdx.x;
    const int half = t >> 8;           // 0 = pred, 1 = obs
    const int ht   = t & 255;          // thread within half
    const int w    = (t >> 6) & 3;     // column (0..3) this wave sorts
    const int L    = t & 63;           // lane

    const float* __restrict__ src = half ? obs : pred;
    float* stage = ls + half * 4096;   // 16 KB staging per half

    // ---- staged load + transpose: 4 chunks of 1024 rows ----
    // chunk q holds rows r with ((r>>4)&3)==q, i.e. e in [16q,16q+16) for every lane.
    // staging slot word(b,s,w) = b*64 + 4*(s^(b&15)) + ((w+(b>>4))&3):
    // reader (lane L=b) banks are exactly 2-way aliased = free.
    float x[EPT];
    const int b_w = ht >> 2;           // writer's lane-slot b (0..63)
    const int s4  = ht & 3;            // writer's s-quad
    #pragma unroll
    for (int q = 0; q < 4; ++q) {
        #pragma unroll
        for (int k = 0; k < 4; ++k) {
            const int s = s4 * 4 + k;                      // 0..15 within chunk
            const int r = b_w * 64 + q * 16 + s;           // global row
            const float4 v = *(const float4*)&src[(size_t)r * NCOL + col0];
            const int base = b_w * 64 + 4 * (s ^ (b_w & 15));
            const int ro   = b_w >> 4;
            stage[base + (( ro    ) & 3)] = v.x;
            stage[base + ((1 + ro) & 3)] = v.y;
            stage[base + ((2 + ro) & 3)] = v.z;
            stage[base + ((3 + ro) & 3)] = v.w;
        }
        __syncthreads();
        #pragma unroll
        for (int s = 0; s < 16; ++s) {
            const int word = L * 64 + 4 * (s ^ (L & 15)) + ((w + (L >> 4)) & 3);
            x[q * 16 + s] = stage[word];
        }
        __syncthreads();
    }

    // ---- phase 1: normalized bitonic sort of my 64 contiguous elements ----
    #pragma unroll
    for (int k = 2; k <= 64; k <<= 1) {
        #pragma unroll
        for (int base = 0; base < EPT; base += k) {
            #pragma unroll
            for (int o = 0; o < k / 2; ++o)
                cemin(x[base + o], x[base + k - 1 - o]);
        }
        #pragma unroll
        for (int j = k / 4; j >= 1; j >>= 1) {
            #pragma unroll
            for (int e = 0; e < EPT; ++e)
                if ((e & j) == 0) cemin(x[e], x[e | j]);
        }
    }

    // ---- phase 2: merges k = 128..4096, all in-wave, no barriers ----
    cross_merge<2>(x, L);
    cross_merge<4>(x, L);
    cross_merge<8>(x, L);
    cross_merge<16>(x, L);
    cross_merge<32>(x, L);
    cross_merge<64>(x, L);

    // ---- epilogue: pred waves park sorted columns in LDS strips (stride 66
    // words -> b64 pair-groups conflict-free), obs waves diff + reduce ----
    __syncthreads();                   // staging region is dead; safe to reuse
    if (half == 0) {
        float* strip = ls + (w * 64 + L) * 66;
        #pragma unroll
        for (int s = 0; s < EPT / 2; ++s)
            *(float2*)&strip[2 * s] = make_float2(x[2 * s], x[2 * s + 1]);
    }
    __syncthreads();
    if (half == 1) {
        const float* strip = ls + (w * 64 + L) * 66;
        float s = 0.0f;
        #pragma unroll
        for (int q = 0; q < EPT / 2; ++q) {
            const float2 p = *(const float2*)&strip[2 * q];
            s += fabsf(x[2 * q] - p.x) + fabsf(x[2 * q + 1] - p.y);
        }
        #pragma unroll
        for (int off = 32; off > 0; off >>= 1)
            s += __shfl_down(s, off, 64);
        if (L == 0)
            atomicAdd(out, s * (1.0f / ((float)NT * (float)NCOL)));
    }
}

extern "C" void kernel_launch(void* const* d_in, const int* in_sizes, int n_in,
                              void* d_out, int out_size, void* d_ws, size_t ws_size,
                              hipStream_t stream) {
    const float* pred = (const float*)d_in[0];
    const float* obs  = (const float*)d_in[1];
    float* out = (float*)d_out;
    hipMemsetAsync(out, 0, sizeof(float), stream);
    wass_kernel<<<NBLOCKS, BLOCK, 0, stream>>>(pred, obs, out);
}